// Round 3
// baseline (1521.341 us; speedup 1.0000x reference)
//
#include <hip/hip_runtime.h>

// GRU: x(512,512) int32, emb(32000,128) f32, W_ih(768,128), W_hh(768,256), b_ih, b_hh.
// out = h_T (512,256) f32.
// Phase A: f32->bf16 converts. Phase B: gi GEMM -> pre-swizzled byte image, coalesced
// stores via LDS transpose. Phase C: 32 blocks x 512 thr recurrence; W_hh in regs,
// 4-deep gi LDS ring with counted-vmcnt raw barriers (one barrier per step).

typedef unsigned short ushort_t;
typedef __attribute__((ext_vector_type(8))) short short8;
typedef __attribute__((ext_vector_type(4))) float float4_;
typedef __attribute__((ext_vector_type(4))) unsigned short ushort4_;
typedef __attribute__((ext_vector_type(2))) unsigned int uint2_;

#define VOCAB 32000
#define EMB 128
#define HID 256
#define G3 768
#define BB 512
#define TT 512
#define SLOT 786432      // gi bytes per timestep: 512*768*2
#define BLK_BYTES 24576  // gi bytes per (t, 16-batch blk): 16*768*2
#define WFIXED 8781824   // emb16 + Wih16 + Whh16

__device__ __forceinline__ float b2f(ushort_t u) {
  return __uint_as_float(((unsigned)u) << 16);
}
__device__ __forceinline__ ushort_t f2b(float f) {
  unsigned u = __float_as_uint(f);
  return (ushort_t)((u + 0x7FFFu + ((u >> 16) & 1u)) >> 16);
}
__device__ __forceinline__ short8 ld8(const ushort_t* p) { return *(const short8*)p; }
__device__ __forceinline__ void gld_lds16(const void* g, void* l) {
  __builtin_amdgcn_global_load_lds((const __attribute__((address_space(1))) void*)g,
                                   (__attribute__((address_space(3))) void*)l, 16, 0, 0);
}
// swizzled byte offset of (batch-local bl, 2*gate) inside a 24576-B tile
__device__ __forceinline__ int gi_byte(int bl, int twog) {
  return ((bl * 1536) + twog) ^ ((bl & 7) << 4);
}

// ---------------- Phase A ----------------
__global__ void cvt_bf16_k(const float* __restrict__ s, ushort_t* __restrict__ d, int n4) {
  int i = blockIdx.x * blockDim.x + threadIdx.x;
  int stride = gridDim.x * blockDim.x;
  for (; i < n4; i += stride) {
    float4_ v = ((const float4_*)s)[i];
    ushort4_ o;
    o.x = f2b(v.x); o.y = f2b(v.y); o.z = f2b(v.z); o.w = f2b(v.w);
    ((ushort4_*)d)[i] = o;
  }
}

// ---------------- Phase B: gi GEMM, coalesced stores via LDS image ----------------
// block (256 thr, 4 waves) owns one batch-blk16 x 2 timesteps; wave w does m-tiles
// w*12..w*12+11; results staged swizzled in LDS, then stored linearly.
__global__ __launch_bounds__(256) void gi_gemm(
    const int* __restrict__ x, const ushort_t* __restrict__ emb16,
    const ushort_t* __restrict__ Wih16, const float* __restrict__ bih,
    const float* __restrict__ bhh, char* __restrict__ gic, int t0, int C) {
  __shared__ float cb[G3];
  __shared__ alignas(16) char img[2][BLK_BYTES];
  const int tid = threadIdx.x;
  for (int i = tid; i < G3; i += 256) cb[i] = bih[i] + (i < 512 ? bhh[i] : 0.f);
  const int lane = tid & 63, w = tid >> 6;
  const int bl = lane & 15, kg = lane >> 4;
  const int blk = blockIdx.x & 31;
  const int tt0 = (blockIdx.x >> 5) * 2;
  const int nj = (C - tt0) < 2 ? 1 : 2;

  short8 bfr[2][4];
#pragma unroll
  for (int j = 0; j < 2; ++j) {
    int tloc = tt0 + (j < nj ? j : 0);
    int tok = x[(blk * 16 + bl) * TT + t0 + tloc];
#pragma unroll
    for (int kt = 0; kt < 4; ++kt)
      bfr[j][kt] = ld8(emb16 + (size_t)tok * EMB + kt * 32 + kg * 8);
  }
  __syncthreads();  // cb ready

#pragma unroll 1
  for (int mi = 0; mi < 12; ++mi) {
    int mt = w * 12 + mi;
    short8 af[4];
#pragma unroll
    for (int kt = 0; kt < 4; ++kt)
      af[kt] = ld8(Wih16 + (mt * 16 + bl) * EMB + kt * 32 + kg * 8);
    float4_ z4 = {0.f, 0.f, 0.f, 0.f};
    float4_ acc[2] = {z4, z4};
#pragma unroll
    for (int kt = 0; kt < 4; ++kt)
#pragma unroll
      for (int j = 0; j < 2; ++j)
        acc[j] = __builtin_amdgcn_mfma_f32_16x16x32_bf16(af[kt], bfr[j][kt], acc[j], 0, 0, 0);
    int byte8 = gi_byte(bl, 32 * mt + 8 * kg);
#pragma unroll
    for (int j = 0; j < 2; ++j) {
      ushort4_ o;
#pragma unroll
      for (int r = 0; r < 4; ++r) o[r] = f2b(acc[j][r] + cb[mt * 16 + kg * 4 + r]);
      *(ushort4_*)(&img[j][byte8]) = o;
    }
  }
  __syncthreads();

#pragma unroll
  for (int j = 0; j < 2; ++j) {
    if (j < nj) {
      char* dst = gic + (size_t)(tt0 + j) * SLOT + (size_t)blk * BLK_BYTES;
#pragma unroll
      for (int c = 0; c < 6; ++c)
        *(float4_*)(dst + c * 4096 + tid * 16) = *(const float4_*)(&img[j][c * 4096 + tid * 16]);
    }
  }
}

// ---------------- Phase C: recurrence ----------------
// 32 blocks x 512 thr (8 waves). Wave w owns m-tiles {w+8i+16q}. 4-deep gi ring,
// raw barriers with counted vmcnt: prefetch issued at t lands for step t+3.
__global__ __launch_bounds__(512, 2) void gru_rec(
    const ushort_t* __restrict__ Whh16, const char* __restrict__ gic,
    const float* __restrict__ bhh, float* __restrict__ out, int t0, int C) {
  __shared__ alignas(16) ushort_t h_lds[2][16 * HID];   // 16 KB, XOR-swizzled bytes
  __shared__ alignas(16) char gi_ring[4][BLK_BYTES];    // 96 KB

  const int tid = threadIdx.x, lane = tid & 63, w = tid >> 6;
  const int bl = lane & 15, kg = lane >> 4;
  const int b0 = blockIdx.x * 16;
  const char* gblk = gic + (size_t)blockIdx.x * BLK_BYTES;

  if (t0 == 0) {
    for (int i = tid; i < 16 * HID; i += 512) h_lds[0][i] = 0;
  } else {
    for (int i = tid; i < 16 * HID; i += 512) {
      int b = i >> 8, k = i & 255;
      *(ushort_t*)((char*)h_lds[0] + (((b << 9) + 2 * k) ^ ((b & 7) << 4))) =
          f2b(out[(size_t)(b0 + b) * HID + k]);
    }
  }

  // W_hh fragments, register/AGPR-resident for all steps.
  short8 wf[2][3][8];
#pragma unroll
  for (int i = 0; i < 2; ++i)
#pragma unroll
    for (int q = 0; q < 3; ++q) {
      int g = (w + 8 * i + 16 * q) * 16 + bl;
#pragma unroll
      for (int kt = 0; kt < 8; ++kt)
        wf[i][q][kt] = ld8(Whh16 + (size_t)g * HID + kt * 32 + kg * 8);
    }

  float4_ bhn[2];
  float hreg[2][4];
#pragma unroll
  for (int i = 0; i < 2; ++i) {
    bhn[i] = *(const float4_*)&bhh[512 + (w + 8 * i) * 16 + kg * 4];
    if (t0 == 0) {
#pragma unroll
      for (int r = 0; r < 4; ++r) hreg[i][r] = 0.f;
    } else {
      float4_ v = *(const float4_*)&out[(size_t)(b0 + bl) * HID + (w + 8 * i) * 16 + kg * 4];
#pragma unroll
      for (int r = 0; r < 4; ++r) hreg[i][r] = v[r];
    }
  }

  // drain prologue vmem + make h_lds[0] visible, then start the pipeline
  asm volatile("s_waitcnt vmcnt(0) lgkmcnt(0)" ::: "memory");
  __builtin_amdgcn_s_barrier();
  __builtin_amdgcn_sched_barrier(0);

#pragma unroll
  for (int tau = 0; tau < 3; ++tau) {
    if (tau < C) {
      const char* src = gblk + (size_t)tau * SLOT + (w * 3) * 1024 + lane * 16;
      char* dst = &gi_ring[tau][(w * 3) * 1024];
#pragma unroll
      for (int ii = 0; ii < 3; ++ii) gld_lds16(src + ii * 1024, dst + ii * 1024);
    }
  }

#pragma unroll 1
  for (int t = 0; t < C; ++t) {
    // counted wait: allow the (up to) 2 newer prefetch groups (3 loads each) to fly.
    int rem = C - 1 - t;
    if (rem >= 2)
      asm volatile("s_waitcnt vmcnt(6) lgkmcnt(0)" ::: "memory");
    else if (rem == 1)
      asm volatile("s_waitcnt vmcnt(3) lgkmcnt(0)" ::: "memory");
    else
      asm volatile("s_waitcnt vmcnt(0) lgkmcnt(0)" ::: "memory");
    __builtin_amdgcn_s_barrier();
    __builtin_amdgcn_sched_barrier(0);

    const int slot = t & 3, cur = t & 1, nxt = cur ^ 1;
    if (t + 3 < C) {
      const char* src = gblk + (size_t)(t + 3) * SLOT + (w * 3) * 1024 + lane * 16;
      char* dst = &gi_ring[(t + 3) & 3][(w * 3) * 1024];
#pragma unroll
      for (int ii = 0; ii < 3; ++ii) gld_lds16(src + ii * 1024, dst + ii * 1024);
    }

    float4_ acc[2][3];
#pragma unroll
    for (int i = 0; i < 2; ++i) {
#pragma unroll
      for (int q = 0; q < 2; ++q) {
        int byte8 = gi_byte(bl, 32 * (w + 8 * i + 16 * q) + 8 * kg);
        ushort4_ v = *(const ushort4_*)(&gi_ring[slot][byte8]);
#pragma unroll
        for (int r = 0; r < 4; ++r) acc[i][q][r] = b2f(v[r]);
      }
      acc[i][2] = bhn[i];
    }

#pragma unroll
    for (int kt = 0; kt < 8; ++kt) {
      int byteoff = ((bl * 512) + kt * 64 + kg * 16) ^ ((bl & 7) << 4);
      short8 bf = *(const short8*)((const char*)h_lds[cur] + byteoff);
#pragma unroll
      for (int i = 0; i < 2; ++i)
#pragma unroll
        for (int q = 0; q < 3; ++q)
          acc[i][q] = __builtin_amdgcn_mfma_f32_16x16x32_bf16(wf[i][q][kt], bf, acc[i][q], 0, 0, 0);
    }

#pragma unroll
    for (int i = 0; i < 2; ++i) {
      int byte8n = gi_byte(bl, 32 * (32 + w + 8 * i) + 8 * kg);
      ushort4_ gv = *(const ushort4_*)(&gi_ring[slot][byte8n]);
#pragma unroll
      for (int r = 0; r < 4; ++r) {
        float rr = __builtin_amdgcn_rcpf(1.f + __expf(-acc[i][0][r]));
        float zz = __builtin_amdgcn_rcpf(1.f + __expf(-acc[i][1][r]));
        float y = b2f(gv[r]) + rr * acc[i][2][r];
        float nn = 1.f - 2.f * __builtin_amdgcn_rcpf(1.f + __expf(2.f * y));
        hreg[i][r] = (1.f - zz) * nn + zz * hreg[i][r];
      }
      int byte0 = (bl * 512 + ((w + 8 * i) * 16 + kg * 4) * 2) ^ ((bl & 7) << 4);
      uint2_ hv;
      hv.x = (unsigned)f2b(hreg[i][0]) | ((unsigned)f2b(hreg[i][1]) << 16);
      hv.y = (unsigned)f2b(hreg[i][2]) | ((unsigned)f2b(hreg[i][3]) << 16);
      *(uint2_*)((char*)h_lds[nxt] + byte0) = hv;
    }
  }

#pragma unroll
  for (int i = 0; i < 2; ++i) {
    float4_ v = {hreg[i][0], hreg[i][1], hreg[i][2], hreg[i][3]};
    *(float4_*)&out[(size_t)(b0 + bl) * HID + (w + 8 * i) * 16 + kg * 4] = v;
  }
}

extern "C" void kernel_launch(void* const* d_in, const int* in_sizes, int n_in,
                              void* d_out, int out_size, void* d_ws, size_t ws_size,
                              hipStream_t stream) {
  const int* x = (const int*)d_in[0];
  const float* emb = (const float*)d_in[1];
  const float* Wih = (const float*)d_in[2];
  const float* Whh = (const float*)d_in[3];
  const float* bih = (const float*)d_in[4];
  const float* bhh = (const float*)d_in[5];
  float* out = (float*)d_out;

  char* ws = (char*)d_ws;
  ushort_t* emb16 = (ushort_t*)ws;
  ushort_t* Wih16 = (ushort_t*)(ws + 8192000);
  ushort_t* Whh16 = (ushort_t*)(ws + 8388608);
  char* gic = ws + WFIXED;

  size_t avail = ws_size > (size_t)WFIXED ? ws_size - (size_t)WFIXED : 0;
  int C = (int)(avail / (size_t)SLOT);
  if (C > TT) C = TT;
  if (C < 1) C = 1;

  cvt_bf16_k<<<1024, 256, 0, stream>>>(emb, emb16, (VOCAB * EMB) / 4);
  cvt_bf16_k<<<96, 256, 0, stream>>>(Wih, Wih16, (G3 * EMB) / 4);
  cvt_bf16_k<<<192, 256, 0, stream>>>(Whh, Whh16, (G3 * HID) / 4);

  for (int t0 = 0; t0 < TT; t0 += C) {
    int Cc = TT - t0 < C ? TT - t0 : C;
    gi_gemm<<<((Cc + 1) / 2) * 32, 256, 0, stream>>>(x, emb16, Wih16, bih, bhh, gic, t0, Cc);
    gru_rec<<<32, 512, 0, stream>>>(Whh16, gic, bhh, out, t0, Cc);
  }
}